// Round 6
// baseline (190.334 us; speedup 1.0000x reference)
//
#include <hip/hip_runtime.h>
#include <math.h>
#include <stdint.h>

// Problem constants (B,C,H,W) = (16,20,256,256), fp32 in, 4 fp32 scalars out.
constexpr int Bn = 16, Cn = 20, Hn = 256, Wn = 256;
constexpr int BCn = Bn * Cn;                 // 320 slices
constexpr int HWn = Hn * Wn;                 // 65536 per slice
constexpr int SPLIT = 8;                     // blocks per slice (R0 geometry)
constexpr int NBLK = BCn * SPLIT;            // 2560 blocks
constexpr int CHUNK = HWn / SPLIT;           // 8192 elems per block
constexpr int TPB = 256;
constexpr int ITERS = CHUNK / (TPB * 4);     // 8 float4 per thread
constexpr int NSLOT = 10;
// ws layout TRANSPOSED: ws[slot * NBLK + blk]  (needs NSLOT*NBLK*4 = 102.4 KB)
// slots: 0 mass, 1 sum(t*y), 2 sum(t*x), 3 sum(p), 4 sum(p*y), 5 sum(p*x),
//        6 sum(p*(y^2+x^2)), 7 SUM(at*om^2*log2(pt)) [x ln2, negated in finalize],
//        8 (pred-t)^2, 9 |pred|
//
// R5 post-mortem: LDS-DMA 6-deep pipeline = 69 us, same ~2.5 TB/s as R0/R2.
// Effective latency under load ~4000 cyc with HBM at 15% -> queueing, not
// saturation. The untested lever all along: R0 was 68 VGPR, 4 regs OVER the
// 64-VGPR occupancy cliff (8 -> 4 waves/SIMD). This round: R0's verified
// structure with (a) x-moment folding + no prefetch pair + #pragma unroll 1
// to get under 64 VGPR naturally (NO launch_bounds min-waves -- R1 proved it
// over-caps to 32 and spills 380 MB), and (b) per-block phase rotation so the
// 2560 blocks don't advance through 32KB-aligned offsets in lockstep.

__device__ inline float wave_reduce(float v) {
    #pragma unroll
    for (int o = 32; o > 0; o >>= 1) v += __shfl_down(v, o, 64);
    return v;
}

__global__ __launch_bounds__(TPB) void partials_kernel(
        const float* __restrict__ pred, const float* __restrict__ target,
        float* __restrict__ ws) {
    const int blk = blockIdx.x;
    const int bc = blk >> 3;                 // / SPLIT
    const int chunk = blk & (SPLIT - 1);
    const long long base = (long long)bc * HWn + (long long)chunk * CHUNK;
    const float4* __restrict__ p4 = (const float4*)(pred + base);
    const float4* __restrict__ t4 = (const float4*)(target + base);
    const int tid = threadIdx.x;

    // Phase rotation: block starts its 8-iteration walk at i0, wraps mod 8.
    // Decorrelates the instantaneous address phase across blocks (8 groups
    // instead of all 2560 blocks hammering the same 32KB-aligned offset).
    const int i0 = (bc + chunk) & (ITERS - 1);

    // Element e = chunk*CHUNK + ii*1024 + tid*4 + j:
    //   x = (tid*4 & 255) + j   (iteration-invariant per lane)
    //   y = chunk*32 + ii*4 + (tid>>6)
    const float x0 = (float)((tid * 4) & 255);
    const float ybase = (float)(chunk * 32 + (tid >> 6));
    constexpr float L2E = 1.44269504088896f; // log2(e)

    float a_mass = 0.f, a_ty = 0.f, a_jt = 0.f, a_p = 0.f, a_py = 0.f,
          a_jp = 0.f, a_pyy = 0.f, a_j2p = 0.f, a_foc = 0.f, a_sq = 0.f,
          a_abs = 0.f;

    #pragma unroll 1
    for (int i = 0; i < ITERS; i++) {
        const int ii = (i + i0) & (ITERS - 1);
        const int idx = ii * TPB + tid;
        const float4 pc = p4[idx];
        const float4 tc = t4[idx];
        const float yf = ybase + (float)(ii << 2);

        const float pv4[4] = {pc.x, pc.y, pc.z, pc.w};
        const float tv4[4] = {tc.x, tc.y, tc.z, tc.w};
        float st4 = 0.f, sp4 = 0.f;
        #pragma unroll
        for (int j = 0; j < 4; j++) {
            const float v = pv4[j];
            const float t = tv4[j];          // exactly 0.0 or 1.0
            // sigmoid + focal in log2 domain (ln2 applied once in finalize):
            // u = v*log2(e); 1-p = e^{-v}*p -> log2(pt) = log2(p) - (1-t)*u
            const float u  = v * L2E;
            const float e  = __builtin_amdgcn_exp2f(-u);
            const float p  = __builtin_amdgcn_rcpf(1.0f + e);   // sigmoid
            const float l2p = __builtin_amdgcn_logf(p);         // log2(p)
            const float l2pt = fmaf(t, u, l2p - u);
            const float om = fmaf(t, fmaf(p, -2.0f, 1.0f), p);  // 1 - pt
            const float at = fmaf(t, -0.5f, 0.75f);             // alpha_t
            a_foc = fmaf(at * l2pt, om * om, a_foc);
            const float d = v - t;
            a_sq = fmaf(d, d, a_sq);
            a_abs += fabsf(v);
            st4 += t;
            sp4 += p;
            if (j == 1)      { a_jt += t;                 a_jp += p;                 a_j2p += p; }
            else if (j == 2) { a_jt = fmaf(t, 2.f, a_jt); a_jp = fmaf(p, 2.f, a_jp); a_j2p = fmaf(p, 4.f, a_j2p); }
            else if (j == 3) { a_jt = fmaf(t, 3.f, a_jt); a_jp = fmaf(p, 3.f, a_jp); a_j2p = fmaf(p, 9.f, a_j2p); }
        }
        a_mass += st4;
        a_ty  = fmaf(st4, yf, a_ty);
        a_p   += sp4;
        a_py  = fmaf(sp4, yf, a_py);
        a_pyy = fmaf(sp4, yf * yf, a_pyy);
    }

    // Fold lane-constant x moments: x = x0 + j
    float slot[NSLOT];
    slot[0] = a_mass;
    slot[1] = a_ty;
    slot[2] = fmaf(x0, a_mass, a_jt);                         // sum t*x
    slot[3] = a_p;
    slot[4] = a_py;
    slot[5] = fmaf(x0, a_p, a_jp);                            // sum p*x
    slot[6] = a_pyy + x0 * x0 * a_p + 2.f * x0 * a_jp + a_j2p;// sum p*(y^2+x^2)
    slot[7] = a_foc;
    slot[8] = a_sq;
    slot[9] = a_abs;

    __shared__ float red[TPB / 64][NSLOT];
    const int lane = tid & 63, wave = tid >> 6;
    #pragma unroll
    for (int k = 0; k < NSLOT; k++) {
        const float r = wave_reduce(slot[k]);
        if (lane == 0) red[wave][k] = r;
    }
    __syncthreads();
    if (tid < NSLOT) {
        float s = 0.f;
        #pragma unroll
        for (int w = 0; w < TPB / 64; w++) s += red[w][tid];
        ws[tid * NBLK + blk] = s;            // transposed store
    }
}

// 320 threads: thread tid owns slice (b,c)=tid. With SPLIT=8 and transposed ws,
// each slot's 8 partials for a slice are two consecutive float4s.
__global__ __launch_bounds__(320) void finalize_kernel(
        const float* __restrict__ ws, float* __restrict__ out) {
    const int tid = threadIdx.x;
    const float4* __restrict__ w4 = (const float4*)ws;

    float s[NSLOT];
    #pragma unroll
    for (int k = 0; k < NSLOT; k++) {
        float a = 0.f;
        #pragma unroll
        for (int q = 0; q < SPLIT / 4; q++) {
            const float4 v = w4[k * (NBLK / 4) + tid * (SPLIT / 4) + q];
            a += v.x + v.y + v.z + v.w;
        }
        s[k] = a;
    }

    // ---- per-(b,c) concentration term ----
    const float mass = s[0];
    const bool valid = mass > 0.f;
    const float sm = valid ? mass : 1.0f;
    const float cy = s[1] / sm, cx = s[2] / sm;
    const float pdsq = s[6] - 2.f * cy * s[4] - 2.f * cx * s[5]
                     + (cy * cy + cx * cx) * s[3];
    float vals[5];
    vals[0] = valid ? (pdsq / (float)HWn) : 0.f;   // conc per-sample mean
    vals[1] = valid ? 1.f : 0.f;                   // n_valid
    vals[2] = s[7];                                // focal sum (log2 domain)
    vals[3] = s[8];                                // sum (pred-t)^2
    vals[4] = s[9];                                // sum |pred|

    __shared__ float lds[5][5];
    const int lane = tid & 63, wave = tid >> 6;
    #pragma unroll
    for (int k = 0; k < 5; k++) {
        const float r = wave_reduce(vals[k]);
        if (lane == 0) lds[wave][k] = r;
    }
    __syncthreads();

    if (tid == 0) {
        float tot[5];
        #pragma unroll
        for (int k = 0; k < 5; k++) {
            float a = 0.f;
            #pragma unroll
            for (int w = 0; w < 5; w++) a += lds[w][k];
            tot[k] = a;
        }
        const float NTOT = (float)Bn * Cn * Hn * Wn;   // 20971520
        constexpr float LN2 = 0.69314718055994531f;
        const float focal = -LN2 * tot[2] / NTOT;      // restore ln from log2
        const float sparsity = tot[3] / NTOT + tot[4] / NTOT;
        const float concentration =
            (tot[1] > 0.f) ? (tot[0] / fmaxf(tot[1], 1.f)) : 0.f;
        const float total = 1.0f * focal + 0.8f * sparsity + 1.5f * concentration;
        out[0] = total;
        out[1] = focal;
        out[2] = sparsity;
        out[3] = concentration;
    }
}

extern "C" void kernel_launch(void* const* d_in, const int* in_sizes, int n_in,
                              void* d_out, int out_size, void* d_ws, size_t ws_size,
                              hipStream_t stream) {
    const float* pred   = (const float*)d_in[0];
    const float* target = (const float*)d_in[1];
    float* out = (float*)d_out;
    float* ws  = (float*)d_ws;   // needs NSLOT*NBLK*4 = 102.4 KB

    partials_kernel<<<NBLK, TPB, 0, stream>>>(pred, target, ws);
    finalize_kernel<<<1, 320, 0, stream>>>(ws, out);
}

// Round 7
// 172.354 us; speedup vs baseline: 1.1043x; 1.1043x over previous
//
#include <hip/hip_runtime.h>
#include <math.h>
#include <stdint.h>

// Problem constants (B,C,H,W) = (16,20,256,256), fp32 in, 4 fp32 scalars out.
constexpr int Bn = 16, Cn = 20, Hn = 256, Wn = 256;
constexpr int BCn = Bn * Cn;                 // 320 slices
constexpr int HWn = Hn * Wn;                 // 65536 per slice
constexpr int SPLIT = 8;                     // blocks per slice
constexpr int NBLK = BCn * SPLIT;            // 2560 blocks
constexpr int CHUNK = HWn / SPLIT;           // 8192 elems per block
constexpr int TPB = 256;
constexpr int ITERS = CHUNK / (TPB * 4);     // 8 float4 per thread
constexpr int NSLOT = 10;
// ws layout TRANSPOSED: ws[slot * NBLK + blk]  (needs NSLOT*NBLK*4 = 102.4 KB)
// slots: 0 mass, 1 sum(t*y), 2 sum(t*x), 3 sum(p), 4 sum(p*y), 5 sum(p*x),
//        6 sum(p*(y^2+x^2)), 7 SUM(at*om^2*log2(pt)) [x ln2, negated in finalize],
//        8 (pred-t)^2, 9 |pred|
//
// R6 post-mortem: occupancy 22->60% at VGPR=28 changed NOTHING (69.5 us).
// Five data points (4 structures + L3-warm dispatch) all pin at 2.4-2.65 TB/s
// effective read BW with HBM 15%, VALU 20%, LDS 0 -> hard ceiling on the
// CU<-L2/L3 read path for a no-reuse stream. This round's single variable:
// NON-TEMPORAL loads (evict-first / read-around) to shift the stream off the
// saturated L3 path onto the HBM path (m13: copy sustains 3.15 TB/s reads
// concurrently with 3.15 TB/s writes, so >2.6 TB/s read service exists).

typedef float f32x4 __attribute__((ext_vector_type(4)));

__device__ inline float wave_reduce(float v) {
    #pragma unroll
    for (int o = 32; o > 0; o >>= 1) v += __shfl_down(v, o, 64);
    return v;
}

__global__ __launch_bounds__(TPB) void partials_kernel(
        const float* __restrict__ pred, const float* __restrict__ target,
        float* __restrict__ ws) {
    const int blk = blockIdx.x;
    const int bc = blk >> 3;                 // / SPLIT
    const int chunk = blk & (SPLIT - 1);
    const long long base = (long long)bc * HWn + (long long)chunk * CHUNK;
    const f32x4* __restrict__ p4 = (const f32x4*)(pred + base);
    const f32x4* __restrict__ t4 = (const f32x4*)(target + base);
    const int tid = threadIdx.x;

    // Element e = chunk*CHUNK + i*1024 + tid*4 + j:
    //   x = (tid*4 & 255) + j   (iteration-invariant per lane)
    //   y = chunk*32 + i*4 + (tid>>6)
    const float x0 = (float)((tid * 4) & 255);
    const float ybase = (float)(chunk * 32 + (tid >> 6));
    constexpr float L2E = 1.44269504088896f; // log2(e)

    float a_mass = 0.f, a_ty = 0.f, a_jt = 0.f, a_p = 0.f, a_py = 0.f,
          a_jp = 0.f, a_pyy = 0.f, a_j2p = 0.f, a_foc = 0.f, a_sq = 0.f,
          a_abs = 0.f;

    #pragma unroll 1
    for (int i = 0; i < ITERS; i++) {
        const int idx = i * TPB + tid;
        // Non-temporal: stream hint, do not displace L2/L3 residents, prefer
        // the HBM service path over the saturated L3 read path.
        const f32x4 pc = __builtin_nontemporal_load(p4 + idx);
        const f32x4 tc = __builtin_nontemporal_load(t4 + idx);
        const float yf = ybase + (float)(i << 2);

        const float pv4[4] = {pc.x, pc.y, pc.z, pc.w};
        const float tv4[4] = {tc.x, tc.y, tc.z, tc.w};
        float st4 = 0.f, sp4 = 0.f;
        #pragma unroll
        for (int j = 0; j < 4; j++) {
            const float v = pv4[j];
            const float t = tv4[j];          // exactly 0.0 or 1.0
            // sigmoid + focal in log2 domain (ln2 applied once in finalize):
            // u = v*log2(e); 1-p = e^{-v}*p -> log2(pt) = log2(p) - (1-t)*u
            const float u  = v * L2E;
            const float e  = __builtin_amdgcn_exp2f(-u);
            const float p  = __builtin_amdgcn_rcpf(1.0f + e);   // sigmoid
            const float l2p = __builtin_amdgcn_logf(p);         // log2(p)
            const float l2pt = fmaf(t, u, l2p - u);
            const float om = fmaf(t, fmaf(p, -2.0f, 1.0f), p);  // 1 - pt
            const float at = fmaf(t, -0.5f, 0.75f);             // alpha_t
            a_foc = fmaf(at * l2pt, om * om, a_foc);
            const float d = v - t;
            a_sq = fmaf(d, d, a_sq);
            a_abs += fabsf(v);
            st4 += t;
            sp4 += p;
            if (j == 1)      { a_jt += t;                 a_jp += p;                 a_j2p += p; }
            else if (j == 2) { a_jt = fmaf(t, 2.f, a_jt); a_jp = fmaf(p, 2.f, a_jp); a_j2p = fmaf(p, 4.f, a_j2p); }
            else if (j == 3) { a_jt = fmaf(t, 3.f, a_jt); a_jp = fmaf(p, 3.f, a_jp); a_j2p = fmaf(p, 9.f, a_j2p); }
        }
        a_mass += st4;
        a_ty  = fmaf(st4, yf, a_ty);
        a_p   += sp4;
        a_py  = fmaf(sp4, yf, a_py);
        a_pyy = fmaf(sp4, yf * yf, a_pyy);
    }

    // Fold lane-constant x moments: x = x0 + j
    float slot[NSLOT];
    slot[0] = a_mass;
    slot[1] = a_ty;
    slot[2] = fmaf(x0, a_mass, a_jt);                         // sum t*x
    slot[3] = a_p;
    slot[4] = a_py;
    slot[5] = fmaf(x0, a_p, a_jp);                            // sum p*x
    slot[6] = a_pyy + x0 * x0 * a_p + 2.f * x0 * a_jp + a_j2p;// sum p*(y^2+x^2)
    slot[7] = a_foc;
    slot[8] = a_sq;
    slot[9] = a_abs;

    __shared__ float red[TPB / 64][NSLOT];
    const int lane = tid & 63, wave = tid >> 6;
    #pragma unroll
    for (int k = 0; k < NSLOT; k++) {
        const float r = wave_reduce(slot[k]);
        if (lane == 0) red[wave][k] = r;
    }
    __syncthreads();
    if (tid < NSLOT) {
        float s = 0.f;
        #pragma unroll
        for (int w = 0; w < TPB / 64; w++) s += red[w][tid];
        ws[tid * NBLK + blk] = s;            // transposed store
    }
}

// 320 threads: thread tid owns slice (b,c)=tid. With SPLIT=8 and transposed ws,
// each slot's 8 partials for a slice are two consecutive float4s.
__global__ __launch_bounds__(320) void finalize_kernel(
        const float* __restrict__ ws, float* __restrict__ out) {
    const int tid = threadIdx.x;
    const float4* __restrict__ w4 = (const float4*)ws;

    float s[NSLOT];
    #pragma unroll
    for (int k = 0; k < NSLOT; k++) {
        float a = 0.f;
        #pragma unroll
        for (int q = 0; q < SPLIT / 4; q++) {
            const float4 v = w4[k * (NBLK / 4) + tid * (SPLIT / 4) + q];
            a += v.x + v.y + v.z + v.w;
        }
        s[k] = a;
    }

    // ---- per-(b,c) concentration term ----
    const float mass = s[0];
    const bool valid = mass > 0.f;
    const float sm = valid ? mass : 1.0f;
    const float cy = s[1] / sm, cx = s[2] / sm;
    const float pdsq = s[6] - 2.f * cy * s[4] - 2.f * cx * s[5]
                     + (cy * cy + cx * cx) * s[3];
    float vals[5];
    vals[0] = valid ? (pdsq / (float)HWn) : 0.f;   // conc per-sample mean
    vals[1] = valid ? 1.f : 0.f;                   // n_valid
    vals[2] = s[7];                                // focal sum (log2 domain)
    vals[3] = s[8];                                // sum (pred-t)^2
    vals[4] = s[9];                                // sum |pred|

    __shared__ float lds[5][5];
    const int lane = tid & 63, wave = tid >> 6;
    #pragma unroll
    for (int k = 0; k < 5; k++) {
        const float r = wave_reduce(vals[k]);
        if (lane == 0) lds[wave][k] = r;
    }
    __syncthreads();

    if (tid == 0) {
        float tot[5];
        #pragma unroll
        for (int k = 0; k < 5; k++) {
            float a = 0.f;
            #pragma unroll
            for (int w = 0; w < 5; w++) a += lds[w][k];
            tot[k] = a;
        }
        const float NTOT = (float)Bn * Cn * Hn * Wn;   // 20971520
        constexpr float LN2 = 0.69314718055994531f;
        const float focal = -LN2 * tot[2] / NTOT;      // restore ln from log2
        const float sparsity = tot[3] / NTOT + tot[4] / NTOT;
        const float concentration =
            (tot[1] > 0.f) ? (tot[0] / fmaxf(tot[1], 1.f)) : 0.f;
        const float total = 1.0f * focal + 0.8f * sparsity + 1.5f * concentration;
        out[0] = total;
        out[1] = focal;
        out[2] = sparsity;
        out[3] = concentration;
    }
}

extern "C" void kernel_launch(void* const* d_in, const int* in_sizes, int n_in,
                              void* d_out, int out_size, void* d_ws, size_t ws_size,
                              hipStream_t stream) {
    const float* pred   = (const float*)d_in[0];
    const float* target = (const float*)d_in[1];
    float* out = (float*)d_out;
    float* ws  = (float*)d_ws;   // needs NSLOT*NBLK*4 = 102.4 KB

    partials_kernel<<<NBLK, TPB, 0, stream>>>(pred, target, ws);
    finalize_kernel<<<1, 320, 0, stream>>>(ws, out);
}

// Round 8
// 170.861 us; speedup vs baseline: 1.1140x; 1.0087x over previous
//
#include <hip/hip_runtime.h>
#include <math.h>
#include <stdint.h>

// Problem constants (B,C,H,W) = (16,20,256,256), fp32 in, 4 fp32 scalars out.
constexpr int Bn = 16, Cn = 20, Hn = 256, Wn = 256;
constexpr int BCn = Bn * Cn;                 // 320 slices
constexpr int HWn = Hn * Wn;                 // 65536 per slice
constexpr int SPLIT = 4;                     // blocks per slice
constexpr int NBLK = BCn * SPLIT;            // 1280 blocks = exactly 5/CU
constexpr int CHUNK = HWn / SPLIT;           // 16384 elems per block
constexpr int TPB = 256;
constexpr int ITERS = CHUNK / (TPB * 4);     // 16 float4 per thread
constexpr int NSLOT = 10;
// ws layout TRANSPOSED: ws[slot * NBLK + blk]  (needs NSLOT*NBLK*4 = 51.2 KB)
// slots: 0 mass, 1 sum(t*y), 2 sum(t*x), 3 sum(p), 4 sum(p*y), 5 sum(p*x),
//        6 sum(p*(y^2+x^2)), 7 SUM(at*om^2*log2(pt)) [x ln2, negated in finalize],
//        8 (pred-t)^2, 9 |pred|
//
// R7 post-mortem: NT loads broke the 2.5 TB/s L3-path pin -> partials ~50 us
// (3.36 TB/s). The harness's own fillBufferAligned sustains 6.7 TB/s
// one-directional, so headroom exists. All previous depth experiments
// (R2 burst, R5 LDS-DMA) ran in the OLD regime where the L3 path was the
// pin -> depth was invisible. This round: single variable = pipeline depth
// in the NT regime. Modulo-4 software pipeline, named float4 pairs, real
// rolling loop (#pragma unroll 1, trip 3) so the R3 hoist-spill can't recur.
// Falsifier built in: if the compiler sinks the refills (R2 mode), VGPR~35;
// honest depth-4 shows VGPR 55-64.

typedef float f32x4 __attribute__((ext_vector_type(4)));

__device__ inline float wave_reduce(float v) {
    #pragma unroll
    for (int o = 32; o > 0; o >>= 1) v += __shfl_down(v, o, 64);
    return v;
}

__global__ __launch_bounds__(TPB) void partials_kernel(
        const float* __restrict__ pred, const float* __restrict__ target,
        float* __restrict__ ws) {
    const int blk = blockIdx.x;
    const int bc = blk >> 2;                 // / SPLIT
    const int chunk = blk & (SPLIT - 1);
    const long long base = (long long)bc * HWn + (long long)chunk * CHUNK;
    const f32x4* __restrict__ p4 = (const f32x4*)(pred + base);
    const f32x4* __restrict__ t4 = (const f32x4*)(target + base);
    const int tid = threadIdx.x;

    // Element e = chunk*CHUNK + i*1024 + tid*4 + j:
    //   x = (tid*4 & 255) + j   (iteration-invariant per lane)
    //   y = chunk*64 + i*4 + (tid>>6)
    const float x0 = (float)((tid * 4) & 255);
    float yf = (float)(chunk * 64 + (tid >> 6));
    constexpr float L2E = 1.44269504088896f; // log2(e)

    float a_mass = 0.f, a_ty = 0.f, a_jt = 0.f, a_p = 0.f, a_py = 0.f,
          a_jp = 0.f, a_pyy = 0.f, a_j2p = 0.f, a_foc = 0.f, a_sq = 0.f,
          a_abs = 0.f;

    auto PROC = [&](const f32x4& pc, const f32x4& tc) {
        const float pv4[4] = {pc.x, pc.y, pc.z, pc.w};
        const float tv4[4] = {tc.x, tc.y, tc.z, tc.w};
        float st4 = 0.f, sp4 = 0.f;
        #pragma unroll
        for (int j = 0; j < 4; j++) {
            const float v = pv4[j];
            const float t = tv4[j];          // exactly 0.0 or 1.0
            // sigmoid + focal in log2 domain (ln2 applied once in finalize):
            // u = v*log2(e); 1-p = e^{-v}*p -> log2(pt) = log2(p) - (1-t)*u
            const float u  = v * L2E;
            const float e  = __builtin_amdgcn_exp2f(-u);
            const float p  = __builtin_amdgcn_rcpf(1.0f + e);   // sigmoid
            const float l2p = __builtin_amdgcn_logf(p);         // log2(p)
            const float l2pt = fmaf(t, u, l2p - u);
            const float om = fmaf(t, fmaf(p, -2.0f, 1.0f), p);  // 1 - pt
            const float at = fmaf(t, -0.5f, 0.75f);             // alpha_t
            a_foc = fmaf(at * l2pt, om * om, a_foc);
            const float d = v - t;
            a_sq = fmaf(d, d, a_sq);
            a_abs += fabsf(v);
            st4 += t;
            sp4 += p;
            if (j == 1)      { a_jt += t;                 a_jp += p;                 a_j2p += p; }
            else if (j == 2) { a_jt = fmaf(t, 2.f, a_jt); a_jp = fmaf(p, 2.f, a_jp); a_j2p = fmaf(p, 4.f, a_j2p); }
            else if (j == 3) { a_jt = fmaf(t, 3.f, a_jt); a_jp = fmaf(p, 3.f, a_jp); a_j2p = fmaf(p, 9.f, a_j2p); }
        }
        a_mass += st4;
        a_ty  = fmaf(st4, yf, a_ty);
        a_p   += sp4;
        a_py  = fmaf(sp4, yf, a_py);
        a_pyy = fmaf(sp4, yf * yf, a_pyy);
        yf += 4.0f;                          // next iteration is 4 rows down
    };

    // ---- depth-4 NT software pipeline ----
    f32x4 P0 = __builtin_nontemporal_load(p4 + 0 * TPB + tid);
    f32x4 T0 = __builtin_nontemporal_load(t4 + 0 * TPB + tid);
    f32x4 P1 = __builtin_nontemporal_load(p4 + 1 * TPB + tid);
    f32x4 T1 = __builtin_nontemporal_load(t4 + 1 * TPB + tid);
    f32x4 P2 = __builtin_nontemporal_load(p4 + 2 * TPB + tid);
    f32x4 T2 = __builtin_nontemporal_load(t4 + 2 * TPB + tid);
    f32x4 P3 = __builtin_nontemporal_load(p4 + 3 * TPB + tid);
    f32x4 T3 = __builtin_nontemporal_load(t4 + 3 * TPB + tid);

    int i = 0;
    #pragma unroll 1
    for (; i + 4 < ITERS; i += 4) {          // i = 0, 4, 8  (3 trips)
        PROC(P0, T0);
        P0 = __builtin_nontemporal_load(p4 + (i + 4) * TPB + tid);
        T0 = __builtin_nontemporal_load(t4 + (i + 4) * TPB + tid);
        PROC(P1, T1);
        P1 = __builtin_nontemporal_load(p4 + (i + 5) * TPB + tid);
        T1 = __builtin_nontemporal_load(t4 + (i + 5) * TPB + tid);
        PROC(P2, T2);
        P2 = __builtin_nontemporal_load(p4 + (i + 6) * TPB + tid);
        T2 = __builtin_nontemporal_load(t4 + (i + 6) * TPB + tid);
        PROC(P3, T3);
        P3 = __builtin_nontemporal_load(p4 + (i + 7) * TPB + tid);
        T3 = __builtin_nontemporal_load(t4 + (i + 7) * TPB + tid);
    }
    PROC(P0, T0); PROC(P1, T1); PROC(P2, T2); PROC(P3, T3);   // drain

    // Fold lane-constant x moments: x = x0 + j
    float slot[NSLOT];
    slot[0] = a_mass;
    slot[1] = a_ty;
    slot[2] = fmaf(x0, a_mass, a_jt);                         // sum t*x
    slot[3] = a_p;
    slot[4] = a_py;
    slot[5] = fmaf(x0, a_p, a_jp);                            // sum p*x
    slot[6] = a_pyy + x0 * x0 * a_p + 2.f * x0 * a_jp + a_j2p;// sum p*(y^2+x^2)
    slot[7] = a_foc;
    slot[8] = a_sq;
    slot[9] = a_abs;

    __shared__ float red[TPB / 64][NSLOT];
    const int lane = tid & 63, wave = tid >> 6;
    #pragma unroll
    for (int k = 0; k < NSLOT; k++) {
        const float r = wave_reduce(slot[k]);
        if (lane == 0) red[wave][k] = r;
    }
    __syncthreads();
    if (tid < NSLOT) {
        float s = 0.f;
        #pragma unroll
        for (int w = 0; w < TPB / 64; w++) s += red[w][tid];
        ws[tid * NBLK + blk] = s;            // transposed store
    }
}

// 320 threads: thread tid owns slice (b,c)=tid. With SPLIT=4 and transposed ws,
// each slot's 4 partials for a slice are exactly one float4 -> 10 vector loads.
__global__ __launch_bounds__(320) void finalize_kernel(
        const float* __restrict__ ws, float* __restrict__ out) {
    const int tid = threadIdx.x;
    const float4* __restrict__ w4 = (const float4*)ws;

    float s[NSLOT];
    #pragma unroll
    for (int k = 0; k < NSLOT; k++) {
        const float4 v = w4[k * (NBLK / 4) + tid];
        s[k] = v.x + v.y + v.z + v.w;
    }

    // ---- per-(b,c) concentration term ----
    const float mass = s[0];
    const bool valid = mass > 0.f;
    const float sm = valid ? mass : 1.0f;
    const float cy = s[1] / sm, cx = s[2] / sm;
    const float pdsq = s[6] - 2.f * cy * s[4] - 2.f * cx * s[5]
                     + (cy * cy + cx * cx) * s[3];
    float vals[5];
    vals[0] = valid ? (pdsq / (float)HWn) : 0.f;   // conc per-sample mean
    vals[1] = valid ? 1.f : 0.f;                   // n_valid
    vals[2] = s[7];                                // focal sum (log2 domain)
    vals[3] = s[8];                                // sum (pred-t)^2
    vals[4] = s[9];                                // sum |pred|

    __shared__ float lds[5][5];
    const int lane = tid & 63, wave = tid >> 6;
    #pragma unroll
    for (int k = 0; k < 5; k++) {
        const float r = wave_reduce(vals[k]);
        if (lane == 0) lds[wave][k] = r;
    }
    __syncthreads();

    if (tid == 0) {
        float tot[5];
        #pragma unroll
        for (int k = 0; k < 5; k++) {
            float a = 0.f;
            #pragma unroll
            for (int w = 0; w < 5; w++) a += lds[w][k];
            tot[k] = a;
        }
        const float NTOT = (float)Bn * Cn * Hn * Wn;   // 20971520
        constexpr float LN2 = 0.69314718055994531f;
        const float focal = -LN2 * tot[2] / NTOT;      // restore ln from log2
        const float sparsity = tot[3] / NTOT + tot[4] / NTOT;
        const float concentration =
            (tot[1] > 0.f) ? (tot[0] / fmaxf(tot[1], 1.f)) : 0.f;
        const float total = 1.0f * focal + 0.8f * sparsity + 1.5f * concentration;
        out[0] = total;
        out[1] = focal;
        out[2] = sparsity;
        out[3] = concentration;
    }
}

extern "C" void kernel_launch(void* const* d_in, const int* in_sizes, int n_in,
                              void* d_out, int out_size, void* d_ws, size_t ws_size,
                              hipStream_t stream) {
    const float* pred   = (const float*)d_in[0];
    const float* target = (const float*)d_in[1];
    float* out = (float*)d_out;
    float* ws  = (float*)d_ws;   // needs NSLOT*NBLK*4 = 51.2 KB

    partials_kernel<<<NBLK, TPB, 0, stream>>>(pred, target, ws);
    finalize_kernel<<<1, 320, 0, stream>>>(ws, out);
}